// Round 7
// baseline (352.901 us; speedup 1.0000x reference)
//
#include <hip/hip_runtime.h>
#include <hip/hip_bf16.h>

typedef __bf16 bf16x8 __attribute__((ext_vector_type(8)));
typedef __bf16 bf16x4 __attribute__((ext_vector_type(4)));
typedef float f32x4 __attribute__((ext_vector_type(4)));

#define BN_EPS 1e-5f

// async global->LDS 16B DMA. LDS dest must be wave-uniform base + lane*16.
__device__ __forceinline__ void gl_lds16(const __bf16* g, __bf16* l) {
    __builtin_amdgcn_global_load_lds(
        (const __attribute__((address_space(1))) unsigned int*)g,
        (__attribute__((address_space(3))) unsigned int*)l,
        16, 0, 0);
}

// ---------------- P1: wd1 permute+cvt: wd1p[n][q*64+oc] = (bf16)wd1[n][oc*64+q] ----------------
__global__ __launch_bounds__(256) void wd1p_kernel(const float* __restrict__ wd1, __bf16* __restrict__ o) {
    __shared__ float t2[64][65];
    const int n = blockIdx.x;
    const int tid = threadIdx.x;
    const float* src = wd1 + (size_t)n * 4096;
    #pragma unroll
    for (int r = 0; r < 16; ++r) {
        int j = r * 256 + tid;            // j = oc*64 + q
        t2[j & 63][j >> 6] = src[j];      // t2[q][oc]
    }
    __syncthreads();
    __bf16* dst = o + (size_t)n * 4096;
    #pragma unroll
    for (int r = 0; r < 16; ++r) {
        int t = r * 256 + tid;            // t = q*64 + oc
        dst[t] = (__bf16)t2[t >> 6][t & 63];
    }
}

// ---------------- P2: combined small prep: wd2 cvt + w1 reorder + w2 reorder ----------------
__global__ void prep_kernel(const float* __restrict__ wd2, const float* __restrict__ w1,
                            const float* __restrict__ w2,
                            __bf16* __restrict__ wd2o, __bf16* __restrict__ w1o,
                            __bf16* __restrict__ w2o) {
    int i = blockIdx.x * 256 + threadIdx.x;
    if (i < 65536) { wd2o[i] = (__bf16)wd2[i]; return; }
    i -= 65536;
    if (i < 4096) {   // w1 [oc][ic][ky][kx] -> [oc][o=(ic*5+ky)][kx pad 8], K=128
        int oc = i >> 7, rem = i & 127;
        int ot = rem >> 3, j = rem & 7;
        float v = 0.f;
        if (ot < 15 && j < 5) {
            int ic = ot / 5, ky = ot % 5;
            v = w1[((oc * 3 + ic) * 5 + ky) * 5 + j];
        }
        w1o[i] = (__bf16)v;
        return;
    }
    i -= 4096;
    if (i < 18432) {  // w2 [oc][ic][tap] -> [oc][tap][ic]
        int oc = i / 288, rem = i % 288;
        int tap = rem / 32, ic = rem % 32;
        w2o[i] = (__bf16)w2[(oc * 32 + ic) * 9 + tap];
    }
}

// feat LDS addressing: [pixel][68 floats], oc chunks of 4 XOR-swizzled by (pixel>>3)&3
__device__ __forceinline__ int feat_addr(int p, int c) {
    return p * 68 + ((((c >> 2) ^ ((p >> 3) & 3)) << 2) | (c & 3));
}

// ---------------- K12: fused conv1(MFMA)+bn+relu + conv2(MFMA)+bn+relu + haar+attn -> f (q-major) ----------------
// one block per image, 256 threads = 4 waves. LDS ~31.8 KB -> 5 blocks/CU.
__global__ __launch_bounds__(256, 5) void conv_fused_kernel(
    const float* __restrict__ x,
    const __bf16* __restrict__ w1r, const float* __restrict__ b1,
    const float* __restrict__ g1, const float* __restrict__ be1,
    const float* __restrict__ m1, const float* __restrict__ v1,
    const __bf16* __restrict__ w2r, const float* __restrict__ b2,
    const float* __restrict__ g2, const float* __restrict__ be2,
    const float* __restrict__ m2, const float* __restrict__ v2,
    const float* __restrict__ wa, const float* __restrict__ ba,
    __bf16* __restrict__ f)
{
    __shared__ __align__(16) __bf16 xsb[3 * 36 * 40];  // 8640 B: padded bf16 input
    __shared__ __align__(16) char  ubuf[23120];        // hs, later overlaid by feat/cd/attn
    __bf16* hsf  = (__bf16*)ubuf;                      // [pixel 17x17][ch stride 40]
    float*  feat = (float*)ubuf;                       // [64 pixels][68] swizzled, 17408 B
    float*  cds  = (float*)(ubuf + 17408);             // [16 yx][68], 4352 B
    float*  atn  = (float*)(ubuf + 21760);             // [4][64], 1024 B

    const int b    = blockIdx.x;
    const int tid  = threadIdx.x;
    const int lane = tid & 63;
    const int wave = tid >> 6;
    const int lo   = lane >> 4;
    const int ln   = lane & 15;

    // ---- phase 0: zero xsb + hs border ----
    {
        bf16x8 z = {};
        for (int i = tid; i < 540; i += 256) *(bf16x8*)&xsb[i * 8] = z;
        if (tid < 132) {
            int pi = tid >> 2, ch = tid & 3;
            int pix = (pi < 17) ? pi : (pi - 16) * 17;
            *(bf16x8*)&hsf[pix * 40 + ch * 8] = z;
        }
    }
    __syncthreads();

    // ---- phase 1: stage x -> xsb bf16: x[ic][iy][ix] -> xsb[ic][iy+2][ix+4] ----
    {
        const float4* xb = (const float4*)(x + (size_t)b * 3072);
        #pragma unroll
        for (int r = 0; r < 3; ++r) {
            int c = r * 256 + tid;
            int plane = c >> 8, rem = c & 255;
            int row = rem >> 3, c4 = rem & 7;
            float4 v = xb[c];
            bf16x4 h;
            h[0] = (__bf16)v.x; h[1] = (__bf16)v.y; h[2] = (__bf16)v.z; h[3] = (__bf16)v.w;
            *(bf16x4*)&xsb[plane * 1440 + (row + 2) * 40 + 4 + c4 * 4] = h;
        }
    }

    // preload conv1 weights (A-operand: lane ln = oc within 16-tile)
    bf16x8 bw1[2][4];
    #pragma unroll
    for (int oct = 0; oct < 2; ++oct)
        #pragma unroll
        for (int s = 0; s < 4; ++s)
            bw1[oct][s] = *(const bf16x8*)(w1r + (oct * 16 + ln) * 128 + (s * 4 + lo) * 8);
    __syncthreads();

    // ---- phase 2: conv1 5x5 s2 p2 as MFMA: A=weights (M=oc), B=patch (N=16 ox), K=128 ----
    f32x4 c1[4][2] = {};   // [mt=oy][oct]
    const unsigned int* xw = (const unsigned int*)xsb;
    #pragma unroll
    for (int s = 0; s < 4; ++s) {
        const int o  = s * 4 + lo;
        const int ic = (o * 205) >> 10;
        const int ky = o - ic * 5;
        const bool dummy = (o == 15);
        const int icc = dummy ? 2 : ic;
        #pragma unroll
        for (int mt = 0; mt < 4; ++mt) {
            const int oy  = wave * 4 + mt;
            const int row = dummy ? 35 : (2 * oy + ky);   // row 35 always zero
            const int dw  = icc * 720 + row * 20 + ln + 1;
            union { unsigned int u[4]; bf16x8 v; } fa;
            fa.u[0] = xw[dw]; fa.u[1] = xw[dw + 1]; fa.u[2] = xw[dw + 2]; fa.u[3] = 0;
            #pragma unroll
            for (int oct = 0; oct < 2; ++oct)
                c1[mt][oct] = __builtin_amdgcn_mfma_f32_16x16x32_bf16(bw1[oct][s], fa.v, c1[mt][oct], 0, 0, 0);
        }
    }

    // ---- BN1 + ReLU -> hs. C layout: row=m=oc-in-tile=lo*4+r, col=n=ox=ln ----
    #pragma unroll
    for (int oct = 0; oct < 2; ++oct) {
        const int ocb = oct * 16 + lo * 4;
        const float4 gv = *(const float4*)(g1 + ocb);
        const float4 vv = *(const float4*)(v1 + ocb);
        const float4 bev = *(const float4*)(be1 + ocb);
        const float4 b1v = *(const float4*)(b1 + ocb);
        const float4 mv = *(const float4*)(m1 + ocb);
        float inv[4], bb[4];
        inv[0] = gv.x * rsqrtf(vv.x + BN_EPS); bb[0] = bev.x + (b1v.x - mv.x) * inv[0];
        inv[1] = gv.y * rsqrtf(vv.y + BN_EPS); bb[1] = bev.y + (b1v.y - mv.y) * inv[1];
        inv[2] = gv.z * rsqrtf(vv.z + BN_EPS); bb[2] = bev.z + (b1v.z - mv.z) * inv[2];
        inv[3] = gv.w * rsqrtf(vv.w + BN_EPS); bb[3] = bev.w + (b1v.w - mv.w) * inv[3];
        #pragma unroll
        for (int mt = 0; mt < 4; ++mt) {
            const int hy = wave * 4 + mt + 1;
            const int hx = ln + 1;
            bf16x4 hv;
            #pragma unroll
            for (int r = 0; r < 4; ++r)
                hv[r] = (__bf16)fmaxf(c1[mt][oct][r] * inv[r] + bb[r], 0.f);
            *(bf16x4*)&hsf[(hy * 17 + hx) * 40 + ocb] = hv;
        }
    }

    const int wm = wave >> 1, wn = wave & 1;
    // conv2 weights (A-operand: lane ln = oc within 16-tile)
    bf16x8 bw2[2][9];
    #pragma unroll
    for (int oct = 0; oct < 2; ++oct) {
        const __bf16* wp = w2r + (wn * 32 + oct * 16 + ln) * 288 + lo * 8;
        #pragma unroll
        for (int ks = 0; ks < 9; ++ks)
            bw2[oct][ks] = *(const bf16x8*)(wp + ks * 32);
    }
    __syncthreads();

    // ---- phase 3: conv2 3x3 s2 p1 as MFMA: A=weights (M=64 oc), B=pixels (N=64), K=288 ----
    f32x4 c2[2][2] = {};   // [oct][np]
    {
        int pixbase[2];
        #pragma unroll
        for (int np = 0; np < 2; ++np) {
            int p = wm * 32 + np * 16 + ln;
            int qy = p >> 3, qx = p & 7;
            pixbase[np] = (2 * qy * 17 + 2 * qx) * 40 + lo * 8;
        }
        #pragma unroll
        for (int ks = 0; ks < 9; ++ks) {
            const int ty = ks / 3, tx = ks % 3;
            bf16x8 bfp[2];
            #pragma unroll
            for (int np = 0; np < 2; ++np)
                bfp[np] = *(const bf16x8*)&hsf[pixbase[np] + (ty * 17 + tx) * 40];
            #pragma unroll
            for (int oct = 0; oct < 2; ++oct)
                #pragma unroll
                for (int np = 0; np < 2; ++np)
                    c2[oct][np] = __builtin_amdgcn_mfma_f32_16x16x32_bf16(bw2[oct][ks], bfp[np], c2[oct][np], 0, 0, 0);
        }
    }
    __syncthreads();   // hs dead after this point; feat overlays it

    // ---- BN2 + ReLU -> feat[pixel][oc] (swizzled chunks, b128 stores) ----
    #pragma unroll
    for (int oct = 0; oct < 2; ++oct) {
        const int ocb = wn * 32 + oct * 16 + lo * 4;
        const float4 gv = *(const float4*)(g2 + ocb);
        const float4 vv = *(const float4*)(v2 + ocb);
        const float4 bev = *(const float4*)(be2 + ocb);
        const float4 b2v = *(const float4*)(b2 + ocb);
        const float4 mv = *(const float4*)(m2 + ocb);
        float inv[4], bb[4];
        inv[0] = gv.x * rsqrtf(vv.x + BN_EPS); bb[0] = bev.x + (b2v.x - mv.x) * inv[0];
        inv[1] = gv.y * rsqrtf(vv.y + BN_EPS); bb[1] = bev.y + (b2v.y - mv.y) * inv[1];
        inv[2] = gv.z * rsqrtf(vv.z + BN_EPS); bb[2] = bev.z + (b2v.z - mv.z) * inv[2];
        inv[3] = gv.w * rsqrtf(vv.w + BN_EPS); bb[3] = bev.w + (b2v.w - mv.w) * inv[3];
        const int j = ocb >> 2;     // oc chunk index
        #pragma unroll
        for (int np = 0; np < 2; ++np) {
            const int p = wm * 32 + np * 16 + ln;
            f32x4 out;
            #pragma unroll
            for (int r = 0; r < 4; ++r)
                out[r] = fmaxf(c2[oct][np][r] * inv[r] + bb[r], 0.f);
            *(f32x4*)&feat[p * 68 + ((j ^ ((p >> 3) & 3)) << 2)] = out;
        }
    }
    __syncthreads();

    // ---- phase 4: Haar cD -> cds[yx][c] (stride 68) ----
    #pragma unroll
    for (int r = 0; r < 4; ++r) {
        int idx = tid * 4 + r;            // 64c x 16yx
        int c = idx >> 4, yx = idx & 15;
        int y = yx >> 2, xx = yx & 3;
        int p00 = 16 * y + 2 * xx;
        float aa = feat[feat_addr(p00, c)];
        float bb = feat[feat_addr(p00 + 1, c)];
        float cc = feat[feat_addr(p00 + 8, c)];
        float dd = feat[feat_addr(p00 + 9, c)];
        cds[yx * 68 + c] = 0.5f * (aa - bb - cc + dd);
    }
    __syncthreads();

    // ---- phase 5: gating + attention (vector feat/cds reads) ----
    const int q  = tid & 63;
    const int g  = wave;
    const int qy2 = q >> 3, qx2 = q & 7;
    const int qq = (qy2 >> 1) * 4 + (qx2 >> 1);
    float a2[16];
    float part = 0.f;
    #pragma unroll
    for (int jj = 0; jj < 4; ++jj) {
        const int j = g * 4 + jj;
        f32x4 fv = *(const f32x4*)&feat[q * 68 + ((j ^ ((q >> 3) & 3)) << 2)];
        f32x4 cv = *(const f32x4*)&cds[qq * 68 + j * 4];
        const float4 wv = *(const float4*)(wa + j * 4);
        float v0 = fv[0] * cv[0], v1x = fv[1] * cv[1], v2x = fv[2] * cv[2], v3 = fv[3] * cv[3];
        a2[jj * 4 + 0] = v0; a2[jj * 4 + 1] = v1x; a2[jj * 4 + 2] = v2x; a2[jj * 4 + 3] = v3;
        part += v0 * wv.x + v1x * wv.y + v2x * wv.z + v3 * wv.w;
    }
    atn[g * 64 + q] = part;
    __syncthreads();
    float s2  = atn[q] + atn[64 + q] + atn[128 + q] + atn[192 + q] + ba[0];
    float sig = 1.f / (1.f + __expf(-s2));

    // ---- write f q-major: f[b][q*64 + oc], 2 x b128 per lane ----
    bf16x8 fo0, fo1;
    #pragma unroll
    for (int j = 0; j < 8; ++j) {
        fo0[j] = (__bf16)(a2[j] * sig);
        fo1[j] = (__bf16)(a2[j + 8] * sig);
    }
    __bf16* fb = f + (size_t)b * 4096 + q * 64 + g * 16;
    *(bf16x8*)fb = fo0;
    *(bf16x8*)(fb + 8) = fo1;
}

// ---------------- K3: dense1 GEMM: C[8192,512] = relu(A[8192,4096] @ B[512,4096]^T + bd1) ----------------
// m97-style: tile 128x128, BK=64, 4 waves 2x2, wave tile 64x64 (acc 4x4). grid (64,4) = 256 blocks.
__global__ __launch_bounds__(256) void gemm1_kernel(
    const __bf16* __restrict__ A, const __bf16* __restrict__ B,
    const float* __restrict__ bias, __bf16* __restrict__ C)
{
    const int K = 4096, NOUT = 512;
    __shared__ __align__(16) __bf16 As[128][64];
    __shared__ __align__(16) __bf16 Bs[128][64];
    const int tid  = threadIdx.x;
    const int lane = tid & 63;
    const int wave = tid >> 6;
    const int wm = wave >> 1, wn = wave & 1;
    const int lo = lane >> 4, ln = lane & 15;
    const int m0 = blockIdx.x * 128, n0 = blockIdx.y * 128;
    const int sw = ln & 7;
    f32x4 acc[4][4] = {};
    for (int k0 = 0; k0 < K; k0 += 64) {
        #pragma unroll
        for (int r = 0; r < 4; ++r) {
            int i = r * 256 + tid;
            int row = i >> 3, cs = i & 7;
            gl_lds16(A + (size_t)(m0 + row) * K + k0 + (cs ^ (row & 7)) * 8, &As[0][0] + i * 8);
        }
        #pragma unroll
        for (int r = 0; r < 4; ++r) {
            int i = r * 256 + tid;
            int row = i >> 3, cs = i & 7;
            gl_lds16(B + (size_t)(n0 + row) * K + k0 + (cs ^ (row & 7)) * 8, &Bs[0][0] + i * 8);
        }
        __syncthreads();
        #pragma unroll
        for (int s = 0; s < 2; ++s) {
            const int c = s * 4 + lo;
            const int slot = (c ^ sw) * 8;
            bf16x8 af[4], bfr[4];
            #pragma unroll
            for (int mt = 0; mt < 4; ++mt)
                af[mt] = *(const bf16x8*)(&As[wm * 64 + mt * 16 + ln][slot]);
            #pragma unroll
            for (int nt = 0; nt < 4; ++nt)
                bfr[nt] = *(const bf16x8*)(&Bs[wn * 64 + nt * 16 + ln][slot]);
            #pragma unroll
            for (int mt = 0; mt < 4; ++mt)
                #pragma unroll
                for (int nt = 0; nt < 4; ++nt)
                    acc[mt][nt] = __builtin_amdgcn_mfma_f32_16x16x32_bf16(af[mt], bfr[nt], acc[mt][nt], 0, 0, 0);
        }
        __syncthreads();
    }
    float bv[4];
    #pragma unroll
    for (int nt = 0; nt < 4; ++nt) bv[nt] = bias[n0 + wn * 64 + nt * 16 + ln];
    #pragma unroll
    for (int mt = 0; mt < 4; ++mt)
        #pragma unroll
        for (int nt = 0; nt < 4; ++nt)
            #pragma unroll
            for (int r = 0; r < 4; ++r) {
                int m = m0 + wm * 64 + mt * 16 + lo * 4 + r;
                int n = n0 + wn * 64 + nt * 16 + ln;
                float v = acc[mt][nt][r] + bv[nt];
                C[(size_t)m * NOUT + n] = (__bf16)fmaxf(v, 0.f);
            }
}

// ---------------- K4: dense2: out[8192,128] = sigmoid(A[8192,512] @ B[128,512]^T + bd2) ----------------
__global__ __launch_bounds__(256) void gemm2_kernel(
    const __bf16* __restrict__ A, const __bf16* __restrict__ B,
    const float* __restrict__ bias, float* __restrict__ Out)
{
    const int K = 512, NOUT = 128;
    __shared__ __align__(16) __bf16 As[64][64];
    __shared__ __align__(16) __bf16 Bs[128][64];
    const int tid  = threadIdx.x;
    const int lane = tid & 63;
    const int wave = tid >> 6;
    const int lo = lane >> 4, ln = lane & 15;
    const int m0 = blockIdx.x * 64;
    const int sw = ln & 7;
    f32x4 acc[4][2] = {};
    for (int k0 = 0; k0 < K; k0 += 64) {
        #pragma unroll
        for (int r = 0; r < 2; ++r) {
            int i = r * 256 + tid;
            int row = i >> 3, cs = i & 7;
            gl_lds16(A + (size_t)(m0 + row) * K + k0 + (cs ^ (row & 7)) * 8, &As[0][0] + i * 8);
        }
        #pragma unroll
        for (int r = 0; r < 4; ++r) {
            int i = r * 256 + tid;
            int row = i >> 3, cs = i & 7;
            gl_lds16(B + (size_t)row * K + k0 + (cs ^ (row & 7)) * 8, &Bs[0][0] + i * 8);
        }
        __syncthreads();
        #pragma unroll
        for (int s = 0; s < 2; ++s) {
            const int c = s * 4 + lo;
            const int slot = (c ^ sw) * 8;
            bf16x8 af[4], bfr[2];
            #pragma unroll
            for (int mt = 0; mt < 4; ++mt)
                af[mt] = *(const bf16x8*)(&As[mt * 16 + ln][slot]);
            #pragma unroll
            for (int nt = 0; nt < 2; ++nt)
                bfr[nt] = *(const bf16x8*)(&Bs[wave * 32 + nt * 16 + ln][slot]);
            #pragma unroll
            for (int mt = 0; mt < 4; ++mt)
                #pragma unroll
                for (int nt = 0; nt < 2; ++nt)
                    acc[mt][nt] = __builtin_amdgcn_mfma_f32_16x16x32_bf16(af[mt], bfr[nt], acc[mt][nt], 0, 0, 0);
        }
        __syncthreads();
    }
    #pragma unroll
    for (int mt = 0; mt < 4; ++mt)
        #pragma unroll
        for (int nt = 0; nt < 2; ++nt)
            #pragma unroll
            for (int r = 0; r < 4; ++r) {
                int m = m0 + mt * 16 + lo * 4 + r;
                int n = wave * 32 + nt * 16 + ln;
                float v = acc[mt][nt][r] + bias[n];
                Out[(size_t)m * NOUT + n] = 1.f / (1.f + __expf(-v));
            }
}

extern "C" void kernel_launch(void* const* d_in, const int* in_sizes, int n_in,
                              void* d_out, int out_size, void* d_ws, size_t ws_size,
                              hipStream_t stream)
{
    const float* x   = (const float*)d_in[0];
    const float* w1  = (const float*)d_in[1];
    const float* b1  = (const float*)d_in[2];
    const float* g1  = (const float*)d_in[3];
    const float* be1 = (const float*)d_in[4];
    const float* m1  = (const float*)d_in[5];
    const float* v1  = (const float*)d_in[6];
    const float* w2  = (const float*)d_in[7];
    const float* b2  = (const float*)d_in[8];
    const float* g2  = (const float*)d_in[9];
    const float* be2 = (const float*)d_in[10];
    const float* m2  = (const float*)d_in[11];
    const float* v2  = (const float*)d_in[12];
    const float* wa  = (const float*)d_in[13];
    const float* ba  = (const float*)d_in[14];
    const float* wd1 = (const float*)d_in[15];
    const float* bd1 = (const float*)d_in[16];
    const float* wd2 = (const float*)d_in[17];
    const float* bd2 = (const float*)d_in[18];

    char* ws = (char*)d_ws;
    __bf16* f_bf   = (__bf16*)(ws);                                       // 64 MiB
    __bf16* h1_bf  = (__bf16*)(ws + 67108864);                            //  8 MiB
    __bf16* wd1_bf = (__bf16*)(ws + 67108864 + 8388608);                  //  4 MiB (permuted)
    __bf16* wd2_bf = (__bf16*)(ws + 67108864 + 8388608 + 4194304);        // 128 KiB
    __bf16* w2r_bf = (__bf16*)(ws + 67108864 + 8388608 + 4194304 + 131072);     // 64 KiB slot
    __bf16* w1r_bf = (__bf16*)(ws + 67108864 + 8388608 + 4194304 + 131072 + 65536); // 8 KiB

    prep_kernel<<<344, 256, 0, stream>>>(wd2, w1, w2, wd2_bf, w1r_bf, w2r_bf);
    wd1p_kernel<<<512, 256, 0, stream>>>(wd1, wd1_bf);

    conv_fused_kernel<<<8192, 256, 0, stream>>>(x, w1r_bf, b1, g1, be1, m1, v1,
                                                w2r_bf, b2, g2, be2, m2, v2, wa, ba, f_bf);

    dim3 g3(64, 4);
    gemm1_kernel<<<g3, 256, 0, stream>>>(f_bf, wd1_bf, bd1, h1_bf);

    gemm2_kernel<<<128, 256, 0, stream>>>(h1_bf, wd2_bf, bd2, (float*)d_out);
}

// Round 8
// 307.411 us; speedup vs baseline: 1.1480x; 1.1480x over previous
//
#include <hip/hip_runtime.h>
#include <hip/hip_bf16.h>

typedef __bf16 bf16x8 __attribute__((ext_vector_type(8)));
typedef __bf16 bf16x4 __attribute__((ext_vector_type(4)));
typedef float f32x4 __attribute__((ext_vector_type(4)));

#define BN_EPS 1e-5f

// async global->LDS 16B DMA. LDS dest must be wave-uniform base + lane*16.
__device__ __forceinline__ void gl_lds16(const __bf16* g, __bf16* l) {
    __builtin_amdgcn_global_load_lds(
        (const __attribute__((address_space(1))) unsigned int*)g,
        (__attribute__((address_space(3))) unsigned int*)l,
        16, 0, 0);
}

// ---------------- P1: wd1 permute+cvt: wd1p[n][q*64+oc] = (bf16)wd1[n][oc*64+q] ----------------
__global__ __launch_bounds__(256) void wd1p_kernel(const float* __restrict__ wd1, __bf16* __restrict__ o) {
    __shared__ float t2[64][65];
    const int n = blockIdx.x;
    const int tid = threadIdx.x;
    const float* src = wd1 + (size_t)n * 4096;
    #pragma unroll
    for (int r = 0; r < 16; ++r) {
        int j = r * 256 + tid;            // j = oc*64 + q
        t2[j & 63][j >> 6] = src[j];      // t2[q][oc]
    }
    __syncthreads();
    __bf16* dst = o + (size_t)n * 4096;
    #pragma unroll
    for (int r = 0; r < 16; ++r) {
        int t = r * 256 + tid;            // t = q*64 + oc
        dst[t] = (__bf16)t2[t >> 6][t & 63];
    }
}

// ---------------- P2: combined small prep: wd2 cvt + w1 reorder + w2 reorder ----------------
__global__ void prep_kernel(const float* __restrict__ wd2, const float* __restrict__ w1,
                            const float* __restrict__ w2,
                            __bf16* __restrict__ wd2o, __bf16* __restrict__ w1o,
                            __bf16* __restrict__ w2o) {
    int i = blockIdx.x * 256 + threadIdx.x;
    if (i < 65536) { wd2o[i] = (__bf16)wd2[i]; return; }
    i -= 65536;
    if (i < 4096) {   // w1 [oc][ic][ky][kx] -> [oc][o=(ic*5+ky)][kx pad 8], K=128
        int oc = i >> 7, rem = i & 127;
        int ot = rem >> 3, j = rem & 7;
        float v = 0.f;
        if (ot < 15 && j < 5) {
            int ic = ot / 5, ky = ot % 5;
            v = w1[((oc * 3 + ic) * 5 + ky) * 5 + j];
        }
        w1o[i] = (__bf16)v;
        return;
    }
    i -= 4096;
    if (i < 18432) {  // w2 [oc][ic][tap] -> [oc][tap][ic]
        int oc = i / 288, rem = i % 288;
        int tap = rem / 32, ic = rem % 32;
        w2o[i] = (__bf16)w2[(oc * 32 + ic) * 9 + tap];
    }
}

// ---------------- K12: fused conv1(MFMA)+bn+relu + conv2(MFMA)+bn+relu + haar+attn -> f (q-major) ----------------
// round-6 version (measured 113 us). one block per image, 256 threads = 4 waves. 5 blocks/CU.
__global__ __launch_bounds__(256, 5) void conv_fused_kernel(
    const float* __restrict__ x,
    const __bf16* __restrict__ w1r, const float* __restrict__ b1,
    const float* __restrict__ g1, const float* __restrict__ be1,
    const float* __restrict__ m1, const float* __restrict__ v1,
    const __bf16* __restrict__ w2r, const float* __restrict__ b2,
    const float* __restrict__ g2, const float* __restrict__ be2,
    const float* __restrict__ m2, const float* __restrict__ v2,
    const float* __restrict__ wa, const float* __restrict__ ba,
    __bf16* __restrict__ f)
{
    __shared__ __align__(16) __bf16 xsb[3 * 36 * 40];  // 8640 B: padded bf16 input
    __shared__ __align__(16) char  ubuf[23120];        // hs, later overlaid by feat/cd/attn
    __bf16* hsf  = (__bf16*)ubuf;                      // [pixel 17x17][ch stride 40]
    float*  feat = (float*)ubuf;                       // [64][64]
    float*  cds  = (float*)(ubuf + 16384);             // [64][16]
    float*  atn  = (float*)(ubuf + 20480);             // [4][64]

    const int b    = blockIdx.x;
    const int tid  = threadIdx.x;
    const int lane = tid & 63;
    const int wave = tid >> 6;
    const int lo   = lane >> 4;
    const int ln   = lane & 15;

    // ---- phase 0: zero xsb + hs border ----
    {
        bf16x8 z = {};
        for (int i = tid; i < 540; i += 256) *(bf16x8*)&xsb[i * 8] = z;
        if (tid < 132) {
            int pi = tid >> 2, ch = tid & 3;
            int pix = (pi < 17) ? pi : (pi - 16) * 17;
            *(bf16x8*)&hsf[pix * 40 + ch * 8] = z;
        }
    }
    __syncthreads();

    // ---- phase 1: stage x -> xsb bf16: x[ic][iy][ix] -> xsb[ic][iy+2][ix+4] ----
    {
        const float4* xb = (const float4*)(x + (size_t)b * 3072);
        #pragma unroll
        for (int r = 0; r < 3; ++r) {
            int c = r * 256 + tid;
            int plane = c >> 8, rem = c & 255;
            int row = rem >> 3, c4 = rem & 7;
            float4 v = xb[c];
            bf16x4 h;
            h[0] = (__bf16)v.x; h[1] = (__bf16)v.y; h[2] = (__bf16)v.z; h[3] = (__bf16)v.w;
            *(bf16x4*)&xsb[plane * 1440 + (row + 2) * 40 + 4 + c4 * 4] = h;
        }
    }

    // preload conv1 weights
    bf16x8 bw1[2][4];
    #pragma unroll
    for (int nt = 0; nt < 2; ++nt)
        #pragma unroll
        for (int s = 0; s < 4; ++s)
            bw1[nt][s] = *(const bf16x8*)(w1r + (nt * 16 + ln) * 128 + (s * 4 + lo) * 8);
    __syncthreads();

    // ---- phase 2: conv1 5x5 s2 p2 as MFMA (M=16 ox, N=32 oc, K=128) ----
    f32x4 c1[4][2] = {};
    const unsigned int* xw = (const unsigned int*)xsb;
    #pragma unroll
    for (int s = 0; s < 4; ++s) {
        const int o  = s * 4 + lo;
        const int ic = (o * 205) >> 10;
        const int ky = o - ic * 5;
        const bool dummy = (o == 15);
        const int icc = dummy ? 2 : ic;
        #pragma unroll
        for (int mt = 0; mt < 4; ++mt) {
            const int oy  = wave * 4 + mt;
            const int row = dummy ? 35 : (2 * oy + ky);   // row 35 always zero
            const int dw  = icc * 720 + row * 20 + ln + 1;
            union { unsigned int u[4]; bf16x8 v; } fa;
            fa.u[0] = xw[dw]; fa.u[1] = xw[dw + 1]; fa.u[2] = xw[dw + 2]; fa.u[3] = 0;
            #pragma unroll
            for (int nt = 0; nt < 2; ++nt)
                c1[mt][nt] = __builtin_amdgcn_mfma_f32_16x16x32_bf16(fa.v, bw1[nt][s], c1[mt][nt], 0, 0, 0);
        }
    }

    // ---- BN1 + ReLU -> hs (channel-last) ----
    #pragma unroll
    for (int nt = 0; nt < 2; ++nt) {
        const int oc  = nt * 16 + ln;
        const float inv = g1[oc] * rsqrtf(v1[oc] + BN_EPS);
        const float bb  = be1[oc] + (b1[oc] - m1[oc]) * inv;
        #pragma unroll
        for (int mt = 0; mt < 4; ++mt) {
            const int hy = wave * 4 + mt + 1;
            #pragma unroll
            for (int r = 0; r < 4; ++r) {
                const int hx = lo * 4 + r + 1;
                hsf[(hy * 17 + hx) * 40 + oc] = (__bf16)fmaxf(c1[mt][nt][r] * inv + bb, 0.f);
            }
        }
    }

    const int wm = wave >> 1, wn = wave & 1;
    bf16x8 bw2[2][9];
    #pragma unroll
    for (int nt = 0; nt < 2; ++nt) {
        const __bf16* wp = w2r + (wn * 32 + nt * 16 + ln) * 288 + lo * 8;
        #pragma unroll
        for (int ks = 0; ks < 9; ++ks)
            bw2[nt][ks] = *(const bf16x8*)(wp + ks * 32);
    }
    __syncthreads();

    // ---- phase 3: conv2 3x3 s2 p1 as MFMA (M=64 pix, N=64 oc, K=288) ----
    f32x4 c2[2][2] = {};
    {
        int pixbase[2];
        #pragma unroll
        for (int mt = 0; mt < 2; ++mt) {
            int p = wm * 32 + mt * 16 + ln;
            int qy = p >> 3, qx = p & 7;
            pixbase[mt] = (2 * qy * 17 + 2 * qx) * 40 + lo * 8;
        }
        #pragma unroll
        for (int ks = 0; ks < 9; ++ks) {
            const int ty = ks / 3, tx = ks % 3;
            bf16x8 af[2];
            #pragma unroll
            for (int mt = 0; mt < 2; ++mt)
                af[mt] = *(const bf16x8*)&hsf[pixbase[mt] + (ty * 17 + tx) * 40];
            #pragma unroll
            for (int mt = 0; mt < 2; ++mt)
                #pragma unroll
                for (int nt = 0; nt < 2; ++nt)
                    c2[mt][nt] = __builtin_amdgcn_mfma_f32_16x16x32_bf16(af[mt], bw2[nt][ks], c2[mt][nt], 0, 0, 0);
        }
    }
    __syncthreads();   // hs dead after this point; feat overlays it

    // ---- BN2 + ReLU -> feat[oc][pixel] ----
    #pragma unroll
    for (int nt = 0; nt < 2; ++nt) {
        const int oc  = wn * 32 + nt * 16 + ln;
        const float inv = g2[oc] * rsqrtf(v2[oc] + BN_EPS);
        const float bb  = be2[oc] + (b2[oc] - m2[oc]) * inv;
        #pragma unroll
        for (int mt = 0; mt < 2; ++mt)
            #pragma unroll
            for (int r = 0; r < 4; ++r) {
                const int p = wm * 32 + mt * 16 + lo * 4 + r;
                feat[oc * 64 + p] = fmaxf(c2[mt][nt][r] * inv + bb, 0.f);
            }
    }
    __syncthreads();

    // ---- phase 4: Haar cD ----
    #pragma unroll
    for (int r = 0; r < 4; ++r) {
        int idx = tid * 4 + r;            // 64c x 16yx
        int c = idx >> 4, yx = idx & 15;
        int y = yx >> 2, xx = yx & 3;
        float aa = feat[c * 64 + (2 * y) * 8 + 2 * xx];
        float bb = feat[c * 64 + (2 * y) * 8 + 2 * xx + 1];
        float cc = feat[c * 64 + (2 * y + 1) * 8 + 2 * xx];
        float dd = feat[c * 64 + (2 * y + 1) * 8 + 2 * xx + 1];
        cds[c * 16 + yx] = 0.5f * (aa - bb - cc + dd);
    }
    __syncthreads();

    // ---- phase 5: gating + attention ----
    const int q  = tid & 63;
    const int g  = wave;
    const int qy2 = q >> 3, qx2 = q & 7;
    const int qq = (qy2 >> 1) * 4 + (qx2 >> 1);
    float a2[16];
    float part = 0.f;
    #pragma unroll
    for (int j = 0; j < 16; ++j) {
        int oc = g * 16 + j;
        float v = feat[oc * 64 + q] * cds[oc * 16 + qq];
        a2[j] = v;
        part += v * wa[oc];
    }
    atn[g * 64 + q] = part;
    __syncthreads();
    float s2  = atn[q] + atn[64 + q] + atn[128 + q] + atn[192 + q] + ba[0];
    float sig = 1.f / (1.f + __expf(-s2));

    // ---- write f q-major: f[b][q*64 + oc], 2 x b128 per lane ----
    bf16x8 fo0, fo1;
    #pragma unroll
    for (int j = 0; j < 8; ++j) {
        fo0[j] = (__bf16)(a2[j] * sig);
        fo1[j] = (__bf16)(a2[j + 8] * sig);
    }
    __bf16* fb = f + (size_t)b * 4096 + q * 64 + g * 16;
    *(bf16x8*)fb = fo0;
    *(bf16x8*)(fb + 8) = fo1;
}

// ---------------- K3a: dense1 split-K GEMM: P[s][8192,512] = A[., sK..sK+2048] @ B^T ----------------
// tile 64(M) x 128(N), BK=64, grid (128,4,2) = 1024 blocks = 4/CU.
__global__ __launch_bounds__(256, 4) void gemm1_split_kernel(
    const __bf16* __restrict__ A, const __bf16* __restrict__ B,
    float* __restrict__ P)
{
    const int K = 4096, NOUT = 512, KH = 2048;
    __shared__ __align__(16) __bf16 As[64][64];
    __shared__ __align__(16) __bf16 Bs[128][64];
    const int tid  = threadIdx.x;
    const int lane = tid & 63;
    const int wave = tid >> 6;
    const int lo = lane >> 4, ln = lane & 15;
    const int m0 = blockIdx.x * 64, n0 = blockIdx.y * 128;
    const int ks0 = blockIdx.z * KH;
    const int sw = ln & 7;
    f32x4 acc[4][2] = {};
    for (int k0 = ks0; k0 < ks0 + KH; k0 += 64) {
        #pragma unroll
        for (int r = 0; r < 2; ++r) {
            int i = r * 256 + tid;
            int row = i >> 3, cs = i & 7;
            gl_lds16(A + (size_t)(m0 + row) * K + k0 + (cs ^ (row & 7)) * 8, &As[0][0] + i * 8);
        }
        #pragma unroll
        for (int r = 0; r < 4; ++r) {
            int i = r * 256 + tid;
            int row = i >> 3, cs = i & 7;
            gl_lds16(B + (size_t)(n0 + row) * K + k0 + (cs ^ (row & 7)) * 8, &Bs[0][0] + i * 8);
        }
        __syncthreads();
        #pragma unroll
        for (int s = 0; s < 2; ++s) {
            const int c = s * 4 + lo;
            const int slot = (c ^ sw) * 8;
            bf16x8 af[4], bfr[2];
            #pragma unroll
            for (int mt = 0; mt < 4; ++mt)
                af[mt] = *(const bf16x8*)(&As[mt * 16 + ln][slot]);
            #pragma unroll
            for (int nt = 0; nt < 2; ++nt)
                bfr[nt] = *(const bf16x8*)(&Bs[wave * 32 + nt * 16 + ln][slot]);
            #pragma unroll
            for (int mt = 0; mt < 4; ++mt)
                #pragma unroll
                for (int nt = 0; nt < 2; ++nt)
                    acc[mt][nt] = __builtin_amdgcn_mfma_f32_16x16x32_bf16(af[mt], bfr[nt], acc[mt][nt], 0, 0, 0);
        }
        __syncthreads();
    }
    float* Pp = P + (size_t)blockIdx.z * 8192 * 512;
    #pragma unroll
    for (int mt = 0; mt < 4; ++mt)
        #pragma unroll
        for (int nt = 0; nt < 2; ++nt)
            #pragma unroll
            for (int r = 0; r < 4; ++r) {
                int m = m0 + mt * 16 + lo * 4 + r;
                int n = n0 + wave * 32 + nt * 16 + ln;
                Pp[(size_t)m * NOUT + n] = acc[mt][nt][r];
            }
}

// ---------------- K3b: reduce: h1 = relu(P0 + P1 + bias) -> bf16 ----------------
__global__ __launch_bounds__(256) void reduce1_kernel(
    const float* __restrict__ P, const float* __restrict__ bias, __bf16* __restrict__ h1)
{
    const size_t HALF = (size_t)8192 * 512;
    size_t i4 = ((size_t)blockIdx.x * 256 + threadIdx.x) * 4;   // element index, 4 at a time
    f32x4 p0 = *(const f32x4*)(P + i4);
    f32x4 p1 = *(const f32x4*)(P + HALF + i4);
    f32x4 bv = *(const f32x4*)(bias + (i4 & 511));
    bf16x4 o;
    #pragma unroll
    for (int j = 0; j < 4; ++j)
        o[j] = (__bf16)fmaxf(p0[j] + p1[j] + bv[j], 0.f);
    *(bf16x4*)(h1 + i4) = o;
}

// ---------------- K3-fallback: round-6 single-pass gemm1 ----------------
__global__ __launch_bounds__(256) void gemm1_kernel(
    const __bf16* __restrict__ A, const __bf16* __restrict__ B,
    const float* __restrict__ bias, __bf16* __restrict__ C)
{
    const int K = 4096, NOUT = 512;
    __shared__ __align__(16) __bf16 As[64][64];
    __shared__ __align__(16) __bf16 Bs[128][64];
    const int tid  = threadIdx.x;
    const int lane = tid & 63;
    const int wave = tid >> 6;
    const int lo = lane >> 4, ln = lane & 15;
    const int m0 = blockIdx.x * 64, n0 = blockIdx.y * 128;
    const int sw = ln & 7;
    f32x4 acc[4][2] = {};
    for (int k0 = 0; k0 < K; k0 += 64) {
        #pragma unroll
        for (int r = 0; r < 2; ++r) {
            int i = r * 256 + tid;
            int row = i >> 3, cs = i & 7;
            gl_lds16(A + (size_t)(m0 + row) * K + k0 + (cs ^ (row & 7)) * 8, &As[0][0] + i * 8);
        }
        #pragma unroll
        for (int r = 0; r < 4; ++r) {
            int i = r * 256 + tid;
            int row = i >> 3, cs = i & 7;
            gl_lds16(B + (size_t)(n0 + row) * K + k0 + (cs ^ (row & 7)) * 8, &Bs[0][0] + i * 8);
        }
        __syncthreads();
        #pragma unroll
        for (int s = 0; s < 2; ++s) {
            const int c = s * 4 + lo;
            const int slot = (c ^ sw) * 8;
            bf16x8 af[4], bfr[2];
            #pragma unroll
            for (int mt = 0; mt < 4; ++mt)
                af[mt] = *(const bf16x8*)(&As[mt * 16 + ln][slot]);
            #pragma unroll
            for (int nt = 0; nt < 2; ++nt)
                bfr[nt] = *(const bf16x8*)(&Bs[wave * 32 + nt * 16 + ln][slot]);
            #pragma unroll
            for (int mt = 0; mt < 4; ++mt)
                #pragma unroll
                for (int nt = 0; nt < 2; ++nt)
                    acc[mt][nt] = __builtin_amdgcn_mfma_f32_16x16x32_bf16(af[mt], bfr[nt], acc[mt][nt], 0, 0, 0);
        }
        __syncthreads();
    }
    #pragma unroll
    for (int mt = 0; mt < 4; ++mt)
        #pragma unroll
        for (int nt = 0; nt < 2; ++nt)
            #pragma unroll
            for (int r = 0; r < 4; ++r) {
                int m = m0 + mt * 16 + lo * 4 + r;
                int n = n0 + wave * 32 + nt * 16 + ln;
                float v = acc[mt][nt][r] + bias[n];
                C[(size_t)m * NOUT + n] = (__bf16)fmaxf(v, 0.f);
            }
}

// ---------------- K4: dense2: out[8192,128] = sigmoid(A[8192,512] @ B[128,512]^T + bd2) ----------------
// tile 32(M) x 128(N), grid 256 blocks.
__global__ __launch_bounds__(256, 4) void gemm2_kernel(
    const __bf16* __restrict__ A, const __bf16* __restrict__ B,
    const float* __restrict__ bias, float* __restrict__ Out)
{
    const int K = 512, NOUT = 128;
    __shared__ __align__(16) __bf16 As[32][64];
    __shared__ __align__(16) __bf16 Bs[128][64];
    const int tid  = threadIdx.x;
    const int lane = tid & 63;
    const int wave = tid >> 6;
    const int lo = lane >> 4, ln = lane & 15;
    const int m0 = blockIdx.x * 32;
    const int sw = ln & 7;
    f32x4 acc[2][2] = {};
    for (int k0 = 0; k0 < K; k0 += 64) {
        {
            int i = tid;                       // 32 rows x 8 chunks = 256
            int row = i >> 3, cs = i & 7;
            gl_lds16(A + (size_t)(m0 + row) * K + k0 + (cs ^ (row & 7)) * 8, &As[0][0] + i * 8);
        }
        #pragma unroll
        for (int r = 0; r < 4; ++r) {
            int i = r * 256 + tid;
            int row = i >> 3, cs = i & 7;
            gl_lds16(B + (size_t)row * K + k0 + (cs ^ (row & 7)) * 8, &Bs[0][0] + i * 8);
        }
        __syncthreads();
        #pragma unroll
        for (int s = 0; s < 2; ++s) {
            const int c = s * 4 + lo;
            const int slot = (c ^ sw) * 8;
            bf16x8 af[2], bfr[2];
            #pragma unroll
            for (int mt = 0; mt < 2; ++mt)
                af[mt] = *(const bf16x8*)(&As[mt * 16 + ln][slot]);
            #pragma unroll
            for (int nt = 0; nt < 2; ++nt)
                bfr[nt] = *(const bf16x8*)(&Bs[wave * 32 + nt * 16 + ln][slot]);
            #pragma unroll
            for (int mt = 0; mt < 2; ++mt)
                #pragma unroll
                for (int nt = 0; nt < 2; ++nt)
                    acc[mt][nt] = __builtin_amdgcn_mfma_f32_16x16x32_bf16(af[mt], bfr[nt], acc[mt][nt], 0, 0, 0);
        }
        __syncthreads();
    }
    #pragma unroll
    for (int mt = 0; mt < 2; ++mt)
        #pragma unroll
        for (int nt = 0; nt < 2; ++nt)
            #pragma unroll
            for (int r = 0; r < 4; ++r) {
                int m = m0 + mt * 16 + lo * 4 + r;
                int n = wave * 32 + nt * 16 + ln;
                float v = acc[mt][nt][r] + bias[n];
                Out[(size_t)m * NOUT + n] = 1.f / (1.f + __expf(-v));
            }
}

extern "C" void kernel_launch(void* const* d_in, const int* in_sizes, int n_in,
                              void* d_out, int out_size, void* d_ws, size_t ws_size,
                              hipStream_t stream)
{
    const float* x   = (const float*)d_in[0];
    const float* w1  = (const float*)d_in[1];
    const float* b1  = (const float*)d_in[2];
    const float* g1  = (const float*)d_in[3];
    const float* be1 = (const float*)d_in[4];
    const float* m1  = (const float*)d_in[5];
    const float* v1  = (const float*)d_in[6];
    const float* w2  = (const float*)d_in[7];
    const float* b2  = (const float*)d_in[8];
    const float* g2  = (const float*)d_in[9];
    const float* be2 = (const float*)d_in[10];
    const float* m2  = (const float*)d_in[11];
    const float* v2  = (const float*)d_in[12];
    const float* wa  = (const float*)d_in[13];
    const float* ba  = (const float*)d_in[14];
    const float* wd1 = (const float*)d_in[15];
    const float* bd1 = (const float*)d_in[16];
    const float* wd2 = (const float*)d_in[17];
    const float* bd2 = (const float*)d_in[18];

    char* ws = (char*)d_ws;
    const size_t SZ_F  = 67108864;          // f: 64 MiB
    const size_t SZ_P  = 33554432;          // partials: 2 x 16 MiB
    const size_t SZ_H1 = 8388608;           // h1: 8 MiB
    const bool use_split = ws_size >= (SZ_F + SZ_P + SZ_H1 + 4194304 + 131072 + 65536 + 8192);

    __bf16* f_bf = (__bf16*)ws;
    float*  P;
    __bf16* h1_bf;
    char* tail;
    if (use_split) {
        P      = (float*)(ws + SZ_F);
        h1_bf  = (__bf16*)(ws + SZ_F + SZ_P);
        tail   = ws + SZ_F + SZ_P + SZ_H1;
    } else {
        P      = nullptr;
        h1_bf  = (__bf16*)(ws + SZ_F);
        tail   = ws + SZ_F + SZ_H1;
    }
    __bf16* wd1_bf = (__bf16*)tail;                       // 4 MiB (permuted)
    __bf16* wd2_bf = (__bf16*)(tail + 4194304);           // 128 KiB
    __bf16* w2r_bf = (__bf16*)(tail + 4194304 + 131072);  // 64 KiB slot
    __bf16* w1r_bf = (__bf16*)(tail + 4194304 + 131072 + 65536); // 8 KiB

    prep_kernel<<<344, 256, 0, stream>>>(wd2, w1, w2, wd2_bf, w1r_bf, w2r_bf);
    wd1p_kernel<<<512, 256, 0, stream>>>(wd1, wd1_bf);

    conv_fused_kernel<<<8192, 256, 0, stream>>>(x, w1r_bf, b1, g1, be1, m1, v1,
                                                w2r_bf, b2, g2, be2, m2, v2, wa, ba, f_bf);

    if (use_split) {
        dim3 g3(128, 4, 2);
        gemm1_split_kernel<<<g3, 256, 0, stream>>>(f_bf, wd1_bf, P);
        reduce1_kernel<<<4096, 256, 0, stream>>>(P, bd1, h1_bf);
    } else {
        dim3 g3(128, 4);
        gemm1_kernel<<<g3, 256, 0, stream>>>(f_bf, wd1_bf, bd1, h1_bf);
    }

    gemm2_kernel<<<256, 256, 0, stream>>>(h1_bf, wd2_bf, bd2, (float*)d_out);
}